// Round 1
// baseline (1185.544 us; speedup 1.0000x reference)
//
#include <hip/hip_runtime.h>

#define DIM 128

// ---------------------------------------------------------------------------
// K0: detect whether edge_index arrived as int64 (reference dtype) or int32
// (harness canonical). For int64 little-endian, every odd int32 word of the
// src half is a high word == 0 (values < 50000). For int32 data those words
// are real edge indices (random in [0,50000)), so 4096 samples all-zero is
// impossible. Writes flag: 1 => int64, 0 => int32. Deterministic every call.
// ---------------------------------------------------------------------------
__global__ void detect_kernel(const int* __restrict__ ei, int E, int* __restrict__ flag) {
    __shared__ int nz;
    if (threadIdx.x == 0) nz = 0;
    __syncthreads();
    int found = 0;
    for (int i = threadIdx.x; i < 4096; i += blockDim.x) {
        if (i < E && ei[2 * i + 1] != 0) found = 1;
    }
    if (found) atomicOr(&nz, 1);
    __syncthreads();
    if (threadIdx.x == 0) *flag = (nz == 0) ? 1 : 0;
}

// K2: deg[dst] += 1.0
__global__ __launch_bounds__(256) void deg_kernel(const int* __restrict__ ei, int E,
                                                  const int* __restrict__ flag,
                                                  float* __restrict__ degf) {
    int is64 = *flag;
    int stride = gridDim.x * blockDim.x;
    for (int e = blockIdx.x * blockDim.x + threadIdx.x; e < E; e += stride) {
        int d = is64 ? ei[2 * (E + e)] : ei[E + e];
        unsafeAtomicAdd(&degf[d], 1.0f);
    }
}

// K3: dis = rsqrt(deg + 1), in place
__global__ __launch_bounds__(256) void dis_kernel(float* __restrict__ degf, int N) {
    int i = blockIdx.x * blockDim.x + threadIdx.x;
    if (i < N) degf[i] = rsqrtf(degf[i] + 1.0f);
}

// K4: agg = x  (pre-add the identity term so the GEMM doesn't re-read x)
__global__ __launch_bounds__(256) void init_kernel(const float4* __restrict__ x4,
                                                   float4* __restrict__ agg4, int n4) {
    int stride = gridDim.x * blockDim.x;
    for (int i = blockIdx.x * blockDim.x + threadIdx.x; i < n4; i += stride)
        agg4[i] = x4[i];
}

// K5: agg[dst] += x[src] * dis[src].  32 lanes per edge, float4 per lane.
__global__ __launch_bounds__(256) void scatter_kernel(const int* __restrict__ ei, int E,
                                                      const int* __restrict__ flag,
                                                      const float* __restrict__ dis,
                                                      const float4* __restrict__ x4,
                                                      float* __restrict__ agg) {
    int is64 = *flag;
    int slot = threadIdx.x >> 5;
    int lane = threadIdx.x & 31;
    int e = blockIdx.x * 8 + slot;
    if (e >= E) return;
    int s = is64 ? ei[2 * e] : ei[e];
    int d = is64 ? ei[2 * (E + e)] : ei[E + e];
    float sc = dis[s];
    float4 v = x4[(size_t)s * 32 + lane];
    float* dst = agg + (size_t)d * 128 + lane * 4;
    unsafeAtomicAdd(dst + 0, v.x * sc);
    unsafeAtomicAdd(dst + 1, v.y * sc);
    unsafeAtomicAdd(dst + 2, v.z * sc);
    unsafeAtomicAdd(dst + 3, v.w * sc);
}

// K6: out = relu((agg * dis) @ W^T)
// Block: 256 threads, 32-row tile. Thread (tr,tc) = (tid/32, tid%32) computes
// rows tr*4+{0..3}, cols tc*4+{0..3}. t-tile staged in LDS (broadcast reads,
// stride 132 keeps the two row-groups of a wave on disjoint banks); W rows
// read as float4 from global (64 KB, L1/L2 resident).
__global__ __launch_bounds__(256) void gemm_relu_kernel(const float* __restrict__ agg,
                                                        const float* __restrict__ dis,
                                                        const float* __restrict__ W,
                                                        float* __restrict__ out, int N) {
    __shared__ __align__(16) float tLds[32][132];
    int tid = threadIdx.x;
    int row0 = blockIdx.x * 32;
#pragma unroll
    for (int i = 0; i < 16; ++i) {
        int idx = i * 256 + tid;
        int r = idx >> 7;
        int k = idx & 127;
        int g = row0 + r;
        tLds[r][k] = (g < N) ? agg[(size_t)g * 128 + k] * dis[g] : 0.0f;
    }
    __syncthreads();
    int tr = tid >> 5, tc = tid & 31;
    float acc[4][4] = {};
    const float4* W4 = (const float4*)W;
#pragma unroll 4
    for (int k4 = 0; k4 < 32; ++k4) {
        float4 a[4], b[4];
#pragma unroll
        for (int rr = 0; rr < 4; ++rr)
            a[rr] = *(const float4*)&tLds[tr * 4 + rr][k4 * 4];
#pragma unroll
        for (int cc = 0; cc < 4; ++cc)
            b[cc] = W4[(size_t)(tc * 4 + cc) * 32 + k4];
#pragma unroll
        for (int rr = 0; rr < 4; ++rr)
#pragma unroll
            for (int cc = 0; cc < 4; ++cc)
                acc[rr][cc] += a[rr].x * b[cc].x + a[rr].y * b[cc].y +
                               a[rr].z * b[cc].z + a[rr].w * b[cc].w;
    }
#pragma unroll
    for (int rr = 0; rr < 4; ++rr) {
        int g = row0 + tr * 4 + rr;
        if (g < N) {
            float4 o;
            o.x = fmaxf(acc[rr][0], 0.0f);
            o.y = fmaxf(acc[rr][1], 0.0f);
            o.z = fmaxf(acc[rr][2], 0.0f);
            o.w = fmaxf(acc[rr][3], 0.0f);
            ((float4*)out)[(size_t)g * 32 + tc] = o;
        }
    }
}

extern "C" void kernel_launch(void* const* d_in, const int* in_sizes, int n_in,
                              void* d_out, int out_size, void* d_ws, size_t ws_size,
                              hipStream_t stream) {
    const float* x = (const float*)d_in[0];
    const int* ei = (const int*)d_in[1];
    const float* W = (const float*)d_in[3];
    float* out = (float*)d_out;

    int N = in_sizes[0] / DIM;
    int E = in_sizes[1] / 2;

    char* ws = (char*)d_ws;
    int* flag = (int*)ws;
    float* degf = (float*)(ws + 256);
    size_t degBytes = (((size_t)N * 4) + 255) & ~(size_t)255;
    float* agg = (float*)(ws + 256 + degBytes);

    hipMemsetAsync(degf, 0, (size_t)N * 4, stream);
    detect_kernel<<<1, 256, 0, stream>>>(ei, E, flag);
    deg_kernel<<<2048, 256, 0, stream>>>(ei, E, flag, degf);
    int nb = (N + 255) / 256;
    dis_kernel<<<nb, 256, 0, stream>>>(degf, N);
    init_kernel<<<2048, 256, 0, stream>>>((const float4*)x, (float4*)agg, N * 32);
    scatter_kernel<<<(E + 7) / 8, 256, 0, stream>>>(ei, E, flag, degf, (const float4*)x, agg);
    gemm_relu_kernel<<<(N + 31) / 32, 256, 0, stream>>>(agg, degf, W, out, N);
}

// Round 2
// 379.329 us; speedup vs baseline: 3.1254x; 3.1254x over previous
//
#include <hip/hip_runtime.h>

#define DIM 128

// ---------------------------------------------------------------------------
// K0: detect whether edge_index arrived as int64 (reference dtype) or int32
// (harness canonical). For int64 little-endian, every odd int32 word of the
// src half is a high word == 0 (values < 50000). For int32 data those words
// are real random edge indices, so 4096 samples all-zero is impossible.
// flag: 1 => int64, 0 => int32.
// ---------------------------------------------------------------------------
__global__ void detect_kernel(const int* __restrict__ ei, int E, int* __restrict__ flag) {
    __shared__ int nz;
    if (threadIdx.x == 0) nz = 0;
    __syncthreads();
    int found = 0;
    for (int i = threadIdx.x; i < 4096; i += blockDim.x) {
        if (i < E && ei[2 * i + 1] != 0) found = 1;
    }
    if (found) atomicOr(&nz, 1);
    __syncthreads();
    if (threadIdx.x == 0) *flag = (nz == 0) ? 1 : 0;
}

// K1: integer in-degree histogram
__global__ __launch_bounds__(256) void deg_kernel(const int* __restrict__ ei, int E,
                                                  const int* __restrict__ flag,
                                                  int* __restrict__ degi) {
    int is64 = *flag;
    int stride = gridDim.x * blockDim.x;
    for (int e = blockIdx.x * blockDim.x + threadIdx.x; e < E; e += stride) {
        int d = is64 ? ei[2 * (E + e)] : ei[E + e];
        atomicAdd(&degi[d], 1);
    }
}

// K2: single-block exclusive prefix scan of degi -> start/cursor; dis = rsqrt(deg+1).
// 1024 threads, each owns ceil(N/1024) contiguous elements; wave shfl-scan of
// per-thread sums + 16-wave LDS scan => 2 barriers total.
__global__ __launch_bounds__(1024) void scan_kernel(const int* __restrict__ degi, int N, int E,
                                                    int* __restrict__ start,
                                                    int* __restrict__ cursor,
                                                    float* __restrict__ dis) {
    __shared__ int wsum[16];
    int tid = threadIdx.x;
    int per = (N + 1023) / 1024;
    int i0 = tid * per;
    int local = 0;
    for (int k = 0; k < per; ++k) {
        int i = i0 + k;
        if (i < N) local += degi[i];
    }
    int lane = tid & 63, wid = tid >> 6;
    int incl = local;
#pragma unroll
    for (int off = 1; off < 64; off <<= 1) {
        int v = __shfl_up(incl, off, 64);
        if (lane >= off) incl += v;
    }
    if (lane == 63) wsum[wid] = incl;
    __syncthreads();
    if (wid == 0 && lane < 16) {
        int v = wsum[lane];
        int s = v;
#pragma unroll
        for (int off = 1; off < 16; off <<= 1) {
            int u = __shfl_up(s, off, 64);
            if (lane >= off) s += u;
        }
        wsum[lane] = s - v;  // exclusive wave prefix
    }
    __syncthreads();
    int base = wsum[wid] + incl - local;  // exclusive prefix for this thread's range
    for (int k = 0; k < per; ++k) {
        int i = i0 + k;
        if (i < N) {
            start[i] = base;
            cursor[i] = base;
            int d = degi[i];
            dis[i] = rsqrtf((float)d + 1.0f);
            base += d;
        }
    }
    if (tid == 0) start[N] = E;
}

// K3: counting-sort scatter of src ids into dst-segmented order
__global__ __launch_bounds__(256) void sortsc_kernel(const int* __restrict__ ei, int E,
                                                     const int* __restrict__ flag,
                                                     int* __restrict__ cursor,
                                                     int* __restrict__ ssrc) {
    int is64 = *flag;
    int stride = gridDim.x * blockDim.x;
    for (int e = blockIdx.x * blockDim.x + threadIdx.x; e < E; e += stride) {
        int s = is64 ? ei[2 * e] : ei[e];
        int d = is64 ? ei[2 * (E + e)] : ei[E + e];
        int p = atomicAdd(&cursor[d], 1);
        ssrc[p] = s;
    }
}

// K4: per-row gather-accumulate, atomic-free.
// t[n] = (x[n] + sum_{s in seg(n)} x[s]*dis[s]) * dis[n]
// 32 lanes per row (float4/lane), 8 rows per 256-thread block.
__global__ __launch_bounds__(256) void gather_kernel(const int* __restrict__ start,
                                                     const int* __restrict__ ssrc,
                                                     const float* __restrict__ dis,
                                                     const float4* __restrict__ x4,
                                                     float4* __restrict__ t4, int N) {
    int g = threadIdx.x >> 5;
    int lane = threadIdx.x & 31;
    int n = blockIdx.x * 8 + g;
    if (n >= N) return;
    int b = start[n], e = start[n + 1];
    float4 acc = x4[(size_t)n * 32 + lane];
    int j = b;
    for (; j + 1 < e; j += 2) {  // 2 independent loads in flight
        int s0 = ssrc[j], s1 = ssrc[j + 1];
        float c0 = dis[s0], c1 = dis[s1];
        float4 v0 = x4[(size_t)s0 * 32 + lane];
        float4 v1 = x4[(size_t)s1 * 32 + lane];
        acc.x += v0.x * c0 + v1.x * c1;
        acc.y += v0.y * c0 + v1.y * c1;
        acc.z += v0.z * c0 + v1.z * c1;
        acc.w += v0.w * c0 + v1.w * c1;
    }
    if (j < e) {
        int s = ssrc[j];
        float c = dis[s];
        float4 v = x4[(size_t)s * 32 + lane];
        acc.x += v.x * c;
        acc.y += v.y * c;
        acc.z += v.z * c;
        acc.w += v.w * c;
    }
    float dn = dis[n];
    acc.x *= dn; acc.y *= dn; acc.z *= dn; acc.w *= dn;
    t4[(size_t)n * 32 + lane] = acc;
}

// K5: out = relu(t @ W^T). 32-row tile in LDS, 4x4 register blocking,
// W rows via float4 through L1 (64 KB resident).
__global__ __launch_bounds__(256) void gemm_relu_kernel(const float4* __restrict__ t4,
                                                        const float* __restrict__ W,
                                                        float* __restrict__ out, int N) {
    __shared__ __align__(16) float tLds[32][132];
    int tid = threadIdx.x;
    int row0 = blockIdx.x * 32;
#pragma unroll
    for (int i = 0; i < 4; ++i) {
        int idx = i * 256 + tid;           // 1024 float4 total
        int r = idx >> 5;                  // row 0..31
        int c4 = idx & 31;                 // float4 col
        int gn = row0 + r;
        float4 v = (gn < N) ? t4[(size_t)gn * 32 + c4] : make_float4(0.f, 0.f, 0.f, 0.f);
        *(float4*)&tLds[r][c4 * 4] = v;    // row stride 132*4=528B, 16B aligned
    }
    __syncthreads();
    int tr = tid >> 5, tc = tid & 31;
    float acc[4][4] = {};
    const float4* W4 = (const float4*)W;
#pragma unroll 4
    for (int k4 = 0; k4 < 32; ++k4) {
        float4 a[4], b[4];
#pragma unroll
        for (int rr = 0; rr < 4; ++rr)
            a[rr] = *(const float4*)&tLds[tr * 4 + rr][k4 * 4];
#pragma unroll
        for (int cc = 0; cc < 4; ++cc)
            b[cc] = W4[(size_t)(tc * 4 + cc) * 32 + k4];
#pragma unroll
        for (int rr = 0; rr < 4; ++rr)
#pragma unroll
            for (int cc = 0; cc < 4; ++cc)
                acc[rr][cc] += a[rr].x * b[cc].x + a[rr].y * b[cc].y +
                               a[rr].z * b[cc].z + a[rr].w * b[cc].w;
    }
#pragma unroll
    for (int rr = 0; rr < 4; ++rr) {
        int g = row0 + tr * 4 + rr;
        if (g < N) {
            float4 o;
            o.x = fmaxf(acc[rr][0], 0.0f);
            o.y = fmaxf(acc[rr][1], 0.0f);
            o.z = fmaxf(acc[rr][2], 0.0f);
            o.w = fmaxf(acc[rr][3], 0.0f);
            ((float4*)out)[(size_t)g * 32 + tc] = o;
        }
    }
}

extern "C" void kernel_launch(void* const* d_in, const int* in_sizes, int n_in,
                              void* d_out, int out_size, void* d_ws, size_t ws_size,
                              hipStream_t stream) {
    const float* x = (const float*)d_in[0];
    const int* ei = (const int*)d_in[1];
    const float* W = (const float*)d_in[3];
    float* out = (float*)d_out;

    int N = in_sizes[0] / DIM;
    int E = in_sizes[1] / 2;

    auto align256 = [](size_t v) { return (v + 255) & ~(size_t)255; };
    char* ws = (char*)d_ws;
    size_t off = 0;
    int* flag = (int*)(ws + off);       off += 256;
    int* degi = (int*)(ws + off);       off += align256((size_t)N * 4);
    int* start = (int*)(ws + off);      off += align256((size_t)(N + 1) * 4);
    int* cursor = (int*)(ws + off);     off += align256((size_t)N * 4);
    float* dis = (float*)(ws + off);    off += align256((size_t)N * 4);
    int* ssrc = (int*)(ws + off);       off += align256((size_t)E * 4);
    float* t = (float*)(ws + off);      // N*128 floats

    hipMemsetAsync(degi, 0, (size_t)N * 4, stream);
    detect_kernel<<<1, 256, 0, stream>>>(ei, E, flag);
    deg_kernel<<<1024, 256, 0, stream>>>(ei, E, flag, degi);
    scan_kernel<<<1, 1024, 0, stream>>>(degi, N, E, start, cursor, dis);
    sortsc_kernel<<<1024, 256, 0, stream>>>(ei, E, flag, cursor, ssrc);
    gather_kernel<<<(N + 7) / 8, 256, 0, stream>>>(start, ssrc, dis, (const float4*)x,
                                                   (float4*)t, N);
    gemm_relu_kernel<<<(N + 31) / 32, 256, 0, stream>>>((const float4*)t, W, out, N);
}

// Round 3
// 233.880 us; speedup vs baseline: 5.0690x; 1.6219x over previous
//
#include <hip/hip_runtime.h>

#define DIM 128
#define SCAN_TILE 1024

// ---------------------------------------------------------------------------
// K0: detect whether edge_index arrived as int64 (reference dtype) or int32
// (harness canonical). For int64 little-endian, every odd int32 word of the
// src half is a high word == 0 (values < 50000). For int32 data those words
// are real random edge indices, so 4096 samples all-zero is impossible.
// flag: 1 => int64, 0 => int32.
// ---------------------------------------------------------------------------
__global__ void detect_kernel(const int* __restrict__ ei, int E, int* __restrict__ flag) {
    __shared__ int nz;
    if (threadIdx.x == 0) nz = 0;
    __syncthreads();
    int found = 0;
    for (int i = threadIdx.x; i < 4096; i += blockDim.x) {
        if (i < E && ei[2 * i + 1] != 0) found = 1;
    }
    if (found) atomicOr(&nz, 1);
    __syncthreads();
    if (threadIdx.x == 0) *flag = (nz == 0) ? 1 : 0;
}

// K1: integer in-degree histogram
__global__ __launch_bounds__(256) void deg_kernel(const int* __restrict__ ei, int E,
                                                  const int* __restrict__ flag,
                                                  int* __restrict__ degi) {
    int is64 = *flag;
    int stride = gridDim.x * blockDim.x;
    for (int e = blockIdx.x * blockDim.x + threadIdx.x; e < E; e += stride) {
        int d = is64 ? ei[2 * (E + e)] : ei[E + e];
        atomicAdd(&degi[d], 1);
    }
}

// K2a: per-tile reduction of degi (tile = SCAN_TILE elements per block)
__global__ __launch_bounds__(256) void bsum_kernel(const int* __restrict__ degi, int N,
                                                   int* __restrict__ bsum) {
    __shared__ int wred[4];
    int base = blockIdx.x * SCAN_TILE;
    int local = 0;
#pragma unroll
    for (int k = 0; k < SCAN_TILE / 256; ++k) {
        int i = base + k * 256 + threadIdx.x;
        if (i < N) local += degi[i];
    }
    int lane = threadIdx.x & 63, wid = threadIdx.x >> 6;
#pragma unroll
    for (int off = 32; off > 0; off >>= 1) local += __shfl_down(local, off, 64);
    if (lane == 0) wred[wid] = local;
    __syncthreads();
    if (threadIdx.x == 0)
        bsum[blockIdx.x] = wred[0] + wred[1] + wred[2] + wred[3];
}

// K2b: single-block exclusive scan of tile sums (NB <= a few hundred)
__global__ __launch_bounds__(256) void bscan_kernel(int* __restrict__ bsum, int NB,
                                                    int* __restrict__ start, int N, int E) {
    __shared__ int wsum[4];
    int tid = threadIdx.x;
    int per = (NB + 255) / 256;
    int i0 = tid * per;
    int local = 0;
    for (int k = 0; k < per; ++k) {
        int i = i0 + k;
        if (i < NB) local += bsum[i];
    }
    int lane = tid & 63, wid = tid >> 6;
    int incl = local;
#pragma unroll
    for (int off = 1; off < 64; off <<= 1) {
        int v = __shfl_up(incl, off, 64);
        if (lane >= off) incl += v;
    }
    if (lane == 63) wsum[wid] = incl;
    __syncthreads();
    if (tid == 0) {
        int a = 0;
#pragma unroll
        for (int w = 0; w < 4; ++w) { int v = wsum[w]; wsum[w] = a; a += v; }
    }
    __syncthreads();
    int base = wsum[wid] + incl - local;
    for (int k = 0; k < per; ++k) {
        int i = i0 + k;
        if (i < NB) { int v = bsum[i]; bsum[i] = base; base += v; }
    }
    if (tid == 0) start[N] = E;
}

// K2c: apply — intra-tile exclusive scan + tile prefix; emit start/cursor/dis
__global__ __launch_bounds__(256) void scan_apply_kernel(const int* __restrict__ degi, int N,
                                                         const int* __restrict__ bsum,
                                                         int* __restrict__ start,
                                                         int* __restrict__ cursor,
                                                         float* __restrict__ dis) {
    __shared__ int wsum[4];
    const int PER = SCAN_TILE / 256;  // 4 contiguous elements per thread
    int tid = threadIdx.x;
    int i0 = blockIdx.x * SCAN_TILE + tid * PER;
    int d[PER];
    int local = 0;
#pragma unroll
    for (int k = 0; k < PER; ++k) {
        int i = i0 + k;
        d[k] = (i < N) ? degi[i] : 0;
        local += d[k];
    }
    int lane = tid & 63, wid = tid >> 6;
    int incl = local;
#pragma unroll
    for (int off = 1; off < 64; off <<= 1) {
        int v = __shfl_up(incl, off, 64);
        if (lane >= off) incl += v;
    }
    if (lane == 63) wsum[wid] = incl;
    __syncthreads();
    if (tid == 0) {
        int a = 0;
#pragma unroll
        for (int w = 0; w < 4; ++w) { int v = wsum[w]; wsum[w] = a; a += v; }
    }
    __syncthreads();
    int pre = bsum[blockIdx.x] + wsum[wid] + incl - local;
#pragma unroll
    for (int k = 0; k < PER; ++k) {
        int i = i0 + k;
        if (i < N) {
            start[i] = pre;
            cursor[i] = pre;
            dis[i] = rsqrtf((float)d[k] + 1.0f);
            pre += d[k];
        }
    }
}

// K3: counting-sort scatter of src ids into dst-segmented order
__global__ __launch_bounds__(256) void sortsc_kernel(const int* __restrict__ ei, int E,
                                                     const int* __restrict__ flag,
                                                     int* __restrict__ cursor,
                                                     int* __restrict__ ssrc) {
    int is64 = *flag;
    int stride = gridDim.x * blockDim.x;
    for (int e = blockIdx.x * blockDim.x + threadIdx.x; e < E; e += stride) {
        int s = is64 ? ei[2 * e] : ei[e];
        int d = is64 ? ei[2 * (E + e)] : ei[E + e];
        int p = atomicAdd(&cursor[d], 1);
        ssrc[p] = s;
    }
}

// K4: per-row gather-accumulate, atomic-free.
// t[n] = (x[n] + sum_{s in seg(n)} x[s]*dis[s]) * dis[n]
// 32 lanes per row (float4/lane), 8 rows per 256-thread block.
__global__ __launch_bounds__(256) void gather_kernel(const int* __restrict__ start,
                                                     const int* __restrict__ ssrc,
                                                     const float* __restrict__ dis,
                                                     const float4* __restrict__ x4,
                                                     float4* __restrict__ t4, int N) {
    int g = threadIdx.x >> 5;
    int lane = threadIdx.x & 31;
    int n = blockIdx.x * 8 + g;
    if (n >= N) return;
    int b = start[n], e = start[n + 1];
    float4 acc = x4[(size_t)n * 32 + lane];
    int j = b;
    for (; j + 1 < e; j += 2) {  // 2 independent loads in flight
        int s0 = ssrc[j], s1 = ssrc[j + 1];
        float c0 = dis[s0], c1 = dis[s1];
        float4 v0 = x4[(size_t)s0 * 32 + lane];
        float4 v1 = x4[(size_t)s1 * 32 + lane];
        acc.x += v0.x * c0 + v1.x * c1;
        acc.y += v0.y * c0 + v1.y * c1;
        acc.z += v0.z * c0 + v1.z * c1;
        acc.w += v0.w * c0 + v1.w * c1;
    }
    if (j < e) {
        int s = ssrc[j];
        float c = dis[s];
        float4 v = x4[(size_t)s * 32 + lane];
        acc.x += v.x * c;
        acc.y += v.y * c;
        acc.z += v.z * c;
        acc.w += v.w * c;
    }
    float dn = dis[n];
    acc.x *= dn; acc.y *= dn; acc.z *= dn; acc.w *= dn;
    t4[(size_t)n * 32 + lane] = acc;
}

// K5: out = relu(t @ W^T). 32-row tile in LDS, 4x4 register blocking,
// W rows via float4 through L1 (64 KB resident).
__global__ __launch_bounds__(256) void gemm_relu_kernel(const float4* __restrict__ t4,
                                                        const float* __restrict__ W,
                                                        float* __restrict__ out, int N) {
    __shared__ __align__(16) float tLds[32][132];
    int tid = threadIdx.x;
    int row0 = blockIdx.x * 32;
#pragma unroll
    for (int i = 0; i < 4; ++i) {
        int idx = i * 256 + tid;           // 1024 float4 total
        int r = idx >> 5;                  // row 0..31
        int c4 = idx & 31;                 // float4 col
        int gn = row0 + r;
        float4 v = (gn < N) ? t4[(size_t)gn * 32 + c4] : make_float4(0.f, 0.f, 0.f, 0.f);
        *(float4*)&tLds[r][c4 * 4] = v;    // row stride 132*4=528B, 16B aligned
    }
    __syncthreads();
    int tr = tid >> 5, tc = tid & 31;
    float acc[4][4] = {};
    const float4* W4 = (const float4*)W;
#pragma unroll 4
    for (int k4 = 0; k4 < 32; ++k4) {
        float4 a[4], b[4];
#pragma unroll
        for (int rr = 0; rr < 4; ++rr)
            a[rr] = *(const float4*)&tLds[tr * 4 + rr][k4 * 4];
#pragma unroll
        for (int cc = 0; cc < 4; ++cc)
            b[cc] = W4[(size_t)(tc * 4 + cc) * 32 + k4];
#pragma unroll
        for (int rr = 0; rr < 4; ++rr)
#pragma unroll
            for (int cc = 0; cc < 4; ++cc)
                acc[rr][cc] += a[rr].x * b[cc].x + a[rr].y * b[cc].y +
                               a[rr].z * b[cc].z + a[rr].w * b[cc].w;
    }
#pragma unroll
    for (int rr = 0; rr < 4; ++rr) {
        int g = row0 + tr * 4 + rr;
        if (g < N) {
            float4 o;
            o.x = fmaxf(acc[rr][0], 0.0f);
            o.y = fmaxf(acc[rr][1], 0.0f);
            o.z = fmaxf(acc[rr][2], 0.0f);
            o.w = fmaxf(acc[rr][3], 0.0f);
            ((float4*)out)[(size_t)g * 32 + tc] = o;
        }
    }
}

extern "C" void kernel_launch(void* const* d_in, const int* in_sizes, int n_in,
                              void* d_out, int out_size, void* d_ws, size_t ws_size,
                              hipStream_t stream) {
    const float* x = (const float*)d_in[0];
    const int* ei = (const int*)d_in[1];
    const float* W = (const float*)d_in[3];
    float* out = (float*)d_out;

    int N = in_sizes[0] / DIM;
    int E = in_sizes[1] / 2;
    int NB = (N + SCAN_TILE - 1) / SCAN_TILE;

    auto align256 = [](size_t v) { return (v + 255) & ~(size_t)255; };
    char* ws = (char*)d_ws;
    size_t off = 0;
    int* flag = (int*)(ws + off);       off += 256;
    int* degi = (int*)(ws + off);       off += align256((size_t)N * 4);
    int* start = (int*)(ws + off);      off += align256((size_t)(N + 1) * 4);
    int* cursor = (int*)(ws + off);     off += align256((size_t)N * 4);
    float* dis = (float*)(ws + off);    off += align256((size_t)N * 4);
    int* bsum = (int*)(ws + off);       off += align256((size_t)NB * 4);
    int* ssrc = (int*)(ws + off);       off += align256((size_t)E * 4);
    float* t = (float*)(ws + off);      // N*128 floats

    hipMemsetAsync(degi, 0, (size_t)N * 4, stream);
    detect_kernel<<<1, 256, 0, stream>>>(ei, E, flag);
    deg_kernel<<<1024, 256, 0, stream>>>(ei, E, flag, degi);
    bsum_kernel<<<NB, 256, 0, stream>>>(degi, N, bsum);
    bscan_kernel<<<1, 256, 0, stream>>>(bsum, NB, start, N, E);
    scan_apply_kernel<<<NB, 256, 0, stream>>>(degi, N, bsum, start, cursor, dis);
    sortsc_kernel<<<1024, 256, 0, stream>>>(ei, E, flag, cursor, ssrc);
    gather_kernel<<<(N + 7) / 8, 256, 0, stream>>>(start, ssrc, dis, (const float4*)x,
                                                   (float4*)t, N);
    gemm_relu_kernel<<<(N + 31) / 32, 256, 0, stream>>>((const float4*)t, W, out, N);
}

// Round 4
// 223.056 us; speedup vs baseline: 5.3150x; 1.0485x over previous
//
#include <hip/hip_runtime.h>

#define DIM 128
#define SCAN_TILE 1024

// ---------------------------------------------------------------------------
// K0: detect whether edge_index arrived as int64 (reference dtype) or int32
// (harness canonical). For int64 little-endian, every odd int32 word of the
// src half is a high word == 0 (values < 50000). For int32 data those words
// are real random edge indices, so 4096 samples all-zero is impossible.
// flag: 1 => int64, 0 => int32.
// ---------------------------------------------------------------------------
__global__ void detect_kernel(const int* __restrict__ ei, int E, int* __restrict__ flag) {
    __shared__ int nz;
    if (threadIdx.x == 0) nz = 0;
    __syncthreads();
    int found = 0;
    for (int i = threadIdx.x; i < 4096; i += blockDim.x) {
        if (i < E && ei[2 * i + 1] != 0) found = 1;
    }
    if (found) atomicOr(&nz, 1);
    __syncthreads();
    if (threadIdx.x == 0) *flag = (nz == 0) ? 1 : 0;
}

// K1: integer in-degree histogram
__global__ __launch_bounds__(256) void deg_kernel(const int* __restrict__ ei, int E,
                                                  const int* __restrict__ flag,
                                                  int* __restrict__ degi) {
    int is64 = *flag;
    int stride = gridDim.x * blockDim.x;
    for (int e = blockIdx.x * blockDim.x + threadIdx.x; e < E; e += stride) {
        int d = is64 ? ei[2 * (E + e)] : ei[E + e];
        atomicAdd(&degi[d], 1);
    }
}

// K2a: per-tile reduction of degi (tile = SCAN_TILE elements per block)
__global__ __launch_bounds__(256) void bsum_kernel(const int* __restrict__ degi, int N,
                                                   int* __restrict__ bsum) {
    __shared__ int wred[4];
    int base = blockIdx.x * SCAN_TILE;
    int local = 0;
#pragma unroll
    for (int k = 0; k < SCAN_TILE / 256; ++k) {
        int i = base + k * 256 + threadIdx.x;
        if (i < N) local += degi[i];
    }
    int lane = threadIdx.x & 63, wid = threadIdx.x >> 6;
#pragma unroll
    for (int off = 32; off > 0; off >>= 1) local += __shfl_down(local, off, 64);
    if (lane == 0) wred[wid] = local;
    __syncthreads();
    if (threadIdx.x == 0)
        bsum[blockIdx.x] = wred[0] + wred[1] + wred[2] + wred[3];
}

// K2b: single-block exclusive scan of tile sums (NB <= a few hundred)
__global__ __launch_bounds__(256) void bscan_kernel(int* __restrict__ bsum, int NB,
                                                    int* __restrict__ start, int N, int E) {
    __shared__ int wsum[4];
    int tid = threadIdx.x;
    int per = (NB + 255) / 256;
    int i0 = tid * per;
    int local = 0;
    for (int k = 0; k < per; ++k) {
        int i = i0 + k;
        if (i < NB) local += bsum[i];
    }
    int lane = tid & 63, wid = tid >> 6;
    int incl = local;
#pragma unroll
    for (int off = 1; off < 64; off <<= 1) {
        int v = __shfl_up(incl, off, 64);
        if (lane >= off) incl += v;
    }
    if (lane == 63) wsum[wid] = incl;
    __syncthreads();
    if (tid == 0) {
        int a = 0;
#pragma unroll
        for (int w = 0; w < 4; ++w) { int v = wsum[w]; wsum[w] = a; a += v; }
    }
    __syncthreads();
    int base = wsum[wid] + incl - local;
    for (int k = 0; k < per; ++k) {
        int i = i0 + k;
        if (i < NB) { int v = bsum[i]; bsum[i] = base; base += v; }
    }
    if (tid == 0) start[N] = E;
}

// K2c: apply — intra-tile exclusive scan + tile prefix; emit start/cursor/dis
__global__ __launch_bounds__(256) void scan_apply_kernel(const int* __restrict__ degi, int N,
                                                         const int* __restrict__ bsum,
                                                         int* __restrict__ start,
                                                         int* __restrict__ cursor,
                                                         float* __restrict__ dis) {
    __shared__ int wsum[4];
    const int PER = SCAN_TILE / 256;  // 4 contiguous elements per thread
    int tid = threadIdx.x;
    int i0 = blockIdx.x * SCAN_TILE + tid * PER;
    int d[PER];
    int local = 0;
#pragma unroll
    for (int k = 0; k < PER; ++k) {
        int i = i0 + k;
        d[k] = (i < N) ? degi[i] : 0;
        local += d[k];
    }
    int lane = tid & 63, wid = tid >> 6;
    int incl = local;
#pragma unroll
    for (int off = 1; off < 64; off <<= 1) {
        int v = __shfl_up(incl, off, 64);
        if (lane >= off) incl += v;
    }
    if (lane == 63) wsum[wid] = incl;
    __syncthreads();
    if (tid == 0) {
        int a = 0;
#pragma unroll
        for (int w = 0; w < 4; ++w) { int v = wsum[w]; wsum[w] = a; a += v; }
    }
    __syncthreads();
    int pre = bsum[blockIdx.x] + wsum[wid] + incl - local;
#pragma unroll
    for (int k = 0; k < PER; ++k) {
        int i = i0 + k;
        if (i < N) {
            start[i] = pre;
            cursor[i] = pre;
            dis[i] = rsqrtf((float)d[k] + 1.0f);
            pre += d[k];
        }
    }
}

// K3: counting-sort scatter of src ids into dst-segmented order
__global__ __launch_bounds__(256) void sortsc_kernel(const int* __restrict__ ei, int E,
                                                     const int* __restrict__ flag,
                                                     int* __restrict__ cursor,
                                                     int* __restrict__ ssrc) {
    int is64 = *flag;
    int stride = gridDim.x * blockDim.x;
    for (int e = blockIdx.x * blockDim.x + threadIdx.x; e < E; e += stride) {
        int s = is64 ? ei[2 * e] : ei[e];
        int d = is64 ? ei[2 * (E + e)] : ei[E + e];
        int p = atomicAdd(&cursor[d], 1);
        ssrc[p] = s;
    }
}

// K4: per-row gather-accumulate, atomic-free.
// t[n] = (x[n] + sum_{s in seg(n)} x[s]*dis[s]) * dis[n]
__global__ __launch_bounds__(256) void gather_kernel(const int* __restrict__ start,
                                                     const int* __restrict__ ssrc,
                                                     const float* __restrict__ dis,
                                                     const float4* __restrict__ x4,
                                                     float4* __restrict__ t4, int N) {
    int g = threadIdx.x >> 5;
    int lane = threadIdx.x & 31;
    int n = blockIdx.x * 8 + g;
    if (n >= N) return;
    int b = start[n], e = start[n + 1];
    float4 acc = x4[(size_t)n * 32 + lane];
    int j = b;
    for (; j + 1 < e; j += 2) {  // 2 independent loads in flight
        int s0 = ssrc[j], s1 = ssrc[j + 1];
        float c0 = dis[s0], c1 = dis[s1];
        float4 v0 = x4[(size_t)s0 * 32 + lane];
        float4 v1 = x4[(size_t)s1 * 32 + lane];
        acc.x += v0.x * c0 + v1.x * c1;
        acc.y += v0.y * c0 + v1.y * c1;
        acc.z += v0.z * c0 + v1.z * c1;
        acc.w += v0.w * c0 + v1.w * c1;
    }
    if (j < e) {
        int s = ssrc[j];
        float c = dis[s];
        float4 v = x4[(size_t)s * 32 + lane];
        acc.x += v.x * c;
        acc.y += v.y * c;
        acc.z += v.z * c;
        acc.w += v.w * c;
    }
    float dn = dis[n];
    acc.x *= dn; acc.y *= dn; acc.z *= dn; acc.w *= dn;
    t4[(size_t)n * 32 + lane] = acc;
}

// K5: out = relu(t @ W^T).
// Block = 256 threads -> 64-row x 128-col output tile.
// W staged once per block in LDS (64 KB, 2 blocks/CU) with XOR-swizzled
// column granules: W[n][4g..4g+3] lives at wlds[n*32 + (g ^ ((n>>2)&7))].
//  - staging: coalesced float4 global reads; fixed-n constant-XOR writes =
//    permutation of contiguous -> conflict-free.
//  - b-read: lanes tc read rows n=4*tc+cc (4-row stride, normally same-bank);
//    granule k4 ^ (tc&7) spreads each 8-lane phase across all 32 banks.
// a-read: t row slices straight from global; all 32 lanes of a half-wave read
// the same 16 B -> broadcast, served by L1 (64-row slab = 32 KB resident).
// Thread (tr=tid>>5, tc=tid&31): rows tr*8+rr, cols tc*4+cc; acc[8][4].
__global__ __launch_bounds__(256) void gemm_relu_kernel(const float4* __restrict__ t4,
                                                        const float4* __restrict__ W4,
                                                        float* __restrict__ out, int N) {
    __shared__ float4 wlds[4096];  // 64 KB exactly
    int tid = threadIdx.x;
#pragma unroll
    for (int i = 0; i < 16; ++i) {
        int idx = i * 256 + tid;
        int n = idx >> 5, g = idx & 31;
        wlds[n * 32 + (g ^ ((n >> 2) & 7))] = W4[idx];
    }
    __syncthreads();

    int tr = tid >> 5, tc = tid & 31;
    int row0 = blockIdx.x * 64 + tr * 8;
    float acc[8][4] = {};

#pragma unroll 2
    for (int k4 = 0; k4 < 32; ++k4) {
        int sw = k4 ^ (tc & 7);
        float4 b[4];
#pragma unroll
        for (int cc = 0; cc < 4; ++cc)
            b[cc] = wlds[(tc * 4 + cc) * 32 + sw];
        float4 a[8];
#pragma unroll
        for (int rr = 0; rr < 8; ++rr) {
            int r = row0 + rr;
            a[rr] = (r < N) ? t4[(size_t)r * 32 + k4]
                            : make_float4(0.f, 0.f, 0.f, 0.f);
        }
#pragma unroll
        for (int rr = 0; rr < 8; ++rr)
#pragma unroll
            for (int cc = 0; cc < 4; ++cc)
                acc[rr][cc] += a[rr].x * b[cc].x + a[rr].y * b[cc].y +
                               a[rr].z * b[cc].z + a[rr].w * b[cc].w;
    }

#pragma unroll
    for (int rr = 0; rr < 8; ++rr) {
        int r = row0 + rr;
        if (r < N) {
            float4 o;
            o.x = fmaxf(acc[rr][0], 0.0f);
            o.y = fmaxf(acc[rr][1], 0.0f);
            o.z = fmaxf(acc[rr][2], 0.0f);
            o.w = fmaxf(acc[rr][3], 0.0f);
            ((float4*)out)[(size_t)r * 32 + tc] = o;
        }
    }
}

extern "C" void kernel_launch(void* const* d_in, const int* in_sizes, int n_in,
                              void* d_out, int out_size, void* d_ws, size_t ws_size,
                              hipStream_t stream) {
    const float* x = (const float*)d_in[0];
    const int* ei = (const int*)d_in[1];
    const float* W = (const float*)d_in[3];
    float* out = (float*)d_out;

    int N = in_sizes[0] / DIM;
    int E = in_sizes[1] / 2;
    int NB = (N + SCAN_TILE - 1) / SCAN_TILE;

    auto align256 = [](size_t v) { return (v + 255) & ~(size_t)255; };
    char* ws = (char*)d_ws;
    size_t off = 0;
    int* flag = (int*)(ws + off);       off += 256;
    int* degi = (int*)(ws + off);       off += align256((size_t)N * 4);
    int* start = (int*)(ws + off);      off += align256((size_t)(N + 1) * 4);
    int* cursor = (int*)(ws + off);     off += align256((size_t)N * 4);
    float* dis = (float*)(ws + off);    off += align256((size_t)N * 4);
    int* bsum = (int*)(ws + off);       off += align256((size_t)NB * 4);
    int* ssrc = (int*)(ws + off);       off += align256((size_t)E * 4);
    float* t = (float*)(ws + off);      // N*128 floats

    hipMemsetAsync(degi, 0, (size_t)N * 4, stream);
    detect_kernel<<<1, 256, 0, stream>>>(ei, E, flag);
    deg_kernel<<<1024, 256, 0, stream>>>(ei, E, flag, degi);
    bsum_kernel<<<NB, 256, 0, stream>>>(degi, N, bsum);
    bscan_kernel<<<1, 256, 0, stream>>>(bsum, NB, start, N, E);
    scan_apply_kernel<<<NB, 256, 0, stream>>>(degi, N, bsum, start, cursor, dis);
    sortsc_kernel<<<1024, 256, 0, stream>>>(ei, E, flag, cursor, ssrc);
    gather_kernel<<<(N + 7) / 8, 256, 0, stream>>>(start, ssrc, dis, (const float4*)x,
                                                   (float4*)t, N);
    gemm_relu_kernel<<<(N + 63) / 64, 256, 0, stream>>>((const float4*)t, (const float4*)W,
                                                        out, N);
}